// Round 10
// baseline (597.337 us; speedup 1.0000x reference)
//
#include <hip/hip_runtime.h>
#include <stdint.h>

#define EMB 128
#define LAYERS 3
#define NGRAPHS 64
#define BN_EPS 1e-5f

typedef short short8 __attribute__((ext_vector_type(8)));
typedef float float4v __attribute__((ext_vector_type(4)));
typedef unsigned short ushort4v __attribute__((ext_vector_type(4)));

__device__ __forceinline__ unsigned short f2bf(float f) {
    union { float f; unsigned int i; } v; v.f = f;
    unsigned int x = v.i;
    unsigned int r = x + 0x7FFFu + ((x >> 16) & 1u);
    return (unsigned short)(r >> 16);
}
__device__ __forceinline__ float bf2f(unsigned short u) {
    union { unsigned int i; float f; } v; v.i = ((unsigned int)u) << 16; return v.f;
}
__device__ __forceinline__ float bflo(unsigned int u) {
    union { unsigned int i; float f; } v; v.i = u << 16; return v.f;
}
__device__ __forceinline__ float bfhi(unsigned int u) {
    union { unsigned int i; float f; } v; v.i = u & 0xffff0000u; return v.f;
}
__device__ __forceinline__ unsigned int packbf(float a, float b) {
    return (unsigned int)f2bf(a) | ((unsigned int)f2bf(b) << 16);
}

// f32 -> bf16 (RNE), three concatenated segments in one dispatch
__global__ __launch_bounds__(256) void conv_bf16_3(
    const float* __restrict__ a, unsigned short* __restrict__ oa, int na,
    const float* __restrict__ b, unsigned short* __restrict__ ob, int nb,
    const float* __restrict__ c, unsigned short* __restrict__ oc, int nc)
{
    int i = blockIdx.x * 256 + threadIdx.x;
    int stride = gridDim.x * 256;
    for (int t = i; t < na + nb + nc; t += stride) {
        if (t < na) oa[t] = f2bf(a[t]);
        else if (t < na + nb) ob[t - na] = f2bf(b[t - na]);
        else oc[t - na - nb] = f2bf(c[t - na - nb]);
    }
}

// ---------------------------------------------------------------------------
// GEMM (input embedding only): C = A[M,K] @ B[Ntot,K]^T + bias
// ---------------------------------------------------------------------------
template<int K, bool A_IS_BF16, bool RELU, bool OUT_BF16>
__global__ __launch_bounds__(256) void gemm_bt(
    const void* __restrict__ Av, const unsigned short* __restrict__ B,
    const float* __restrict__ bias, void* __restrict__ Cv,
    int M, int Ntot)
{
    const int wave = threadIdx.x >> 6;
    const int lane = threadIdx.x & 63;
    const int q    = lane >> 4;
    const int ln   = lane & 15;
    const int m_base = blockIdx.x * 64 + wave * 16;
    const int n_base = blockIdx.y * 64;

    float4v acc[4];
#pragma unroll
    for (int i = 0; i < 4; ++i) acc[i] = (float4v){0.f, 0.f, 0.f, 0.f};

    int mrow = m_base + ln;
    if (mrow >= M) mrow = M - 1;

    const int KSTEPS = K / 32;
#pragma unroll
    for (int ks = 0; ks < KSTEPS; ++ks) {
        const int k0 = ks * 32 + q * 8;
        short8 afrag;
        if constexpr (A_IS_BF16) {
            const unsigned short* A = (const unsigned short*)Av;
            afrag = *reinterpret_cast<const short8*>(A + (size_t)mrow * K + k0);
        } else {
            const float* A = (const float*)Av;
            const float4v* p = reinterpret_cast<const float4v*>(A + (size_t)mrow * K + k0);
            float4v f0 = p[0], f1 = p[1];
            afrag[0] = (short)f2bf(f0[0]); afrag[1] = (short)f2bf(f0[1]);
            afrag[2] = (short)f2bf(f0[2]); afrag[3] = (short)f2bf(f0[3]);
            afrag[4] = (short)f2bf(f1[0]); afrag[5] = (short)f2bf(f1[1]);
            afrag[6] = (short)f2bf(f1[2]); afrag[7] = (short)f2bf(f1[3]);
        }
#pragma unroll
        for (int nt = 0; nt < 4; ++nt) {
            const short8 bfrag = *reinterpret_cast<const short8*>(
                B + (size_t)(n_base + nt * 16 + ln) * K + k0);
            acc[nt] = __builtin_amdgcn_mfma_f32_16x16x32_bf16(afrag, bfrag, acc[nt], 0, 0, 0);
        }
    }

#pragma unroll
    for (int nt = 0; nt < 4; ++nt) {
        const int n = n_base + nt * 16 + ln;
        const float bv = bias[n];
#pragma unroll
        for (int r = 0; r < 4; ++r) {
            const int m = m_base + q * 4 + r;
            if (m < M) {
                float v = acc[nt][r] + bv;
                if constexpr (RELU) v = v > 0.f ? v : 0.f;
                if constexpr (OUT_BF16)
                    ((unsigned short*)Cv)[(size_t)m * Ntot + n] = f2bf(v);
                else
                    ((float*)Cv)[(size_t)m * Ntot + n] = v;
            }
        }
    }
}

// ---------------------------------------------------------------------------
// Fused MLP v3: weights register-resident, node-streaming; h2 out = bf16.
// Block = 512 thr (8 waves). Wave w holds W1 rows [w*32,+32) and W2 rows
// [w*16,+16) in VGPRs, loaded ONCE; grid-strides over 16-node tiles.
// BN partial stats from exact f32 accumulators, striped into sums2[32][256].
// ---------------------------------------------------------------------------
__global__ __launch_bounds__(512) void fused_mlp(
    const unsigned short* __restrict__ ag, const unsigned short* __restrict__ W1,
    const float* __restrict__ b1, const unsigned short* __restrict__ W2,
    const float* __restrict__ b2, unsigned short* __restrict__ h2b,
    float* __restrict__ sums2, int M, int ntiles)
{
    __shared__ unsigned short ag_lds[16 * 136];
    __shared__ unsigned short Ylds[16 * 264];
    const int tid = threadIdx.x;
    const int wave = tid >> 6, lane = tid & 63;
    const int q = lane >> 4, ln = lane & 15;
    const int k0 = q * 8;
    float* slice = sums2 + (size_t)(blockIdx.x & 31) * 256;

    // --- resident weight fragments (once per block) ---
    short8 w1f[2][4], w2f[8];
#pragma unroll
    for (int c = 0; c < 2; ++c) {
        const int ct = wave * 2 + c;
#pragma unroll
        for (int ks = 0; ks < 4; ++ks)
            w1f[c][ks] = *reinterpret_cast<const short8*>(
                W1 + (size_t)(ct * 16 + ln) * 128 + ks * 32 + k0);
    }
#pragma unroll
    for (int ks = 0; ks < 8; ++ks)
        w2f[ks] = *reinterpret_cast<const short8*>(
            W2 + (size_t)(wave * 16 + ln) * 256 + ks * 32 + k0);
    float4v b1v[2];
    b1v[0] = *reinterpret_cast<const float4v*>(b1 + (wave * 2) * 16 + q * 4);
    b1v[1] = *reinterpret_cast<const float4v*>(b1 + (wave * 2 + 1) * 16 + q * 4);
    const float4v b2v = *reinterpret_cast<const float4v*>(b2 + wave * 16 + q * 4);

    for (int t = blockIdx.x; t < ntiles; t += gridDim.x) {
        const int nbase = t * 16;
        __syncthreads();   // previous iteration's LDS readers done
        {
            const int nd = tid >> 5, ch = (tid & 31) * 4;
            int ng = nbase + nd; if (ng >= M) ng = M - 1;
            *reinterpret_cast<uint2*>(&ag_lds[nd * 136 + ch]) =
                *reinterpret_cast<const uint2*>(ag + (size_t)ng * 128 + ch);
        }
        __syncthreads();

        // stage 1: Y^T tile (channels x nodes)
        short8 agf[4];
#pragma unroll
        for (int ks = 0; ks < 4; ++ks)
            agf[ks] = *reinterpret_cast<const short8*>(
                &ag_lds[ln * 136 + ks * 32 + k0]);
#pragma unroll
        for (int c = 0; c < 2; ++c) {
            float4v acc = (float4v){0.f, 0.f, 0.f, 0.f};
#pragma unroll
            for (int ks = 0; ks < 4; ++ks)
                acc = __builtin_amdgcn_mfma_f32_16x16x32_bf16(
                    w1f[c][ks], agf[ks], acc, 0, 0, 0);
            const int c0 = (wave * 2 + c) * 16 + q * 4;
            ushort4v pk;
            pk[0] = f2bf(fmaxf(acc[0] + b1v[c][0], 0.f));
            pk[1] = f2bf(fmaxf(acc[1] + b1v[c][1], 0.f));
            pk[2] = f2bf(fmaxf(acc[2] + b1v[c][2], 0.f));
            pk[3] = f2bf(fmaxf(acc[3] + b1v[c][3], 0.f));
            *reinterpret_cast<ushort4v*>(&Ylds[ln * 264 + c0]) = pk;
        }
        __syncthreads();

        // stage 2: h2 tile
        short8 yf[8];
#pragma unroll
        for (int ks = 0; ks < 8; ++ks)
            yf[ks] = *reinterpret_cast<const short8*>(
                &Ylds[ln * 264 + ks * 32 + k0]);
        float4v acc = (float4v){0.f, 0.f, 0.f, 0.f};
#pragma unroll
        for (int ks = 0; ks < 8; ++ks)
            acc = __builtin_amdgcn_mfma_f32_16x16x32_bf16(
                w2f[ks], yf[ks], acc, 0, 0, 0);
        const int node = nbase + ln;
        const bool valid = (node < M);
        const int c0 = wave * 16 + q * 4;
        float4v v;
        v[0] = acc[0] + b2v[0]; v[1] = acc[1] + b2v[1];
        v[2] = acc[2] + b2v[2]; v[3] = acc[3] + b2v[3];
        if (valid) {
            ushort4v pk;
            pk[0] = f2bf(v[0]); pk[1] = f2bf(v[1]);
            pk[2] = f2bf(v[2]); pk[3] = f2bf(v[3]);
            *reinterpret_cast<ushort4v*>(h2b + (size_t)node * 128 + c0) = pk;
        }

        float s[4], s2[4];
#pragma unroll
        for (int r = 0; r < 4; ++r) {
            const float x = valid ? v[r] : 0.f;
            s[r] = x; s2[r] = x * x;
        }
#pragma unroll
        for (int off = 1; off < 16; off <<= 1) {
#pragma unroll
            for (int r = 0; r < 4; ++r) {
                s[r]  += __shfl_xor(s[r],  off);
                s2[r] += __shfl_xor(s2[r], off);
            }
        }
        if (ln == 0) {
#pragma unroll
            for (int r = 0; r < 4; ++r) {
                atomicAdd(&slice[c0 + r], s[r]);
                atomicAdd(&slice[128 + c0 + r], s2[r]);
            }
        }
    }
}

// ---------------------------------------------------------------------------
// Fold 32 striped stat slices into per-channel BN (scale, shift)
// ---------------------------------------------------------------------------
__global__ __launch_bounds__(128) void bn_coef(
    const float* __restrict__ sums2, const float* __restrict__ gamma,
    const float* __restrict__ beta, float* __restrict__ coef, float invN)
{
    const int c = threadIdx.x;
    float s = 0.f, ss = 0.f;
    for (int k = 0; k < 32; ++k) {
        s  += sums2[k * 256 + c];
        ss += sums2[k * 256 + 128 + c];
    }
    float mu = s * invN;
    float var = ss * invN - mu * mu;
    float sc = gamma[c] * rsqrtf(fmaxf(var, 0.f) + BN_EPS);
    coef[c] = sc;
    coef[128 + c] = beta[c] - mu * sc;
}

// ---------------------------------------------------------------------------
// CSR build: histogram, 3-phase parallel scan, fill (src only -> 4B writes)
// ---------------------------------------------------------------------------
__global__ __launch_bounds__(256) void hist_kernel(
    const int* __restrict__ ei, int* __restrict__ deg_cnt, int E)
{
    int e = blockIdx.x * 256 + threadIdx.x;
    if (e < E) atomicAdd(&deg_cnt[ei[E + e]], 1);
}

__global__ __launch_bounds__(256) void scan_part(
    const int* __restrict__ deg, int* __restrict__ blocksum, int n)
{
    int i = blockIdx.x * 256 + threadIdx.x;
    int v = (i < n) ? deg[i] : 0;
    const int lane = threadIdx.x & 63;
#pragma unroll
    for (int off = 32; off > 0; off >>= 1) v += __shfl_down(v, off);
    __shared__ int ws[4];
    if (lane == 0) ws[threadIdx.x >> 6] = v;
    __syncthreads();
    if (threadIdx.x == 0)
        blocksum[blockIdx.x] = ws[0] + ws[1] + ws[2] + ws[3];
}

__global__ __launch_bounds__(256) void scan_top(
    int* __restrict__ blocksum, int nblk)
{
    const int t = threadIdx.x;
    int v = (t < nblk) ? blocksum[t] : 0;
    const int lane = t & 63, wv = t >> 6;
    int iv = v;
#pragma unroll
    for (int off = 1; off < 64; off <<= 1) {
        int u = __shfl_up(iv, off);
        if (lane >= off) iv += u;
    }
    __shared__ int ws[4];
    if (lane == 63) ws[wv] = iv;
    __syncthreads();
    int woff = 0;
    for (int j = 0; j < wv; ++j) woff += ws[j];
    if (t < nblk) blocksum[t] = woff + iv - v;
}

__global__ __launch_bounds__(256) void scan_emit(
    const int* __restrict__ deg, const int* __restrict__ blockoff,
    int* __restrict__ rowptr, int* __restrict__ wp, int n)
{
    int i = blockIdx.x * 256 + threadIdx.x;
    int v = (i < n) ? deg[i] : 0;
    const int lane = threadIdx.x & 63, wv = threadIdx.x >> 6;
    int iv = v;
#pragma unroll
    for (int off = 1; off < 64; off <<= 1) {
        int u = __shfl_up(iv, off);
        if (lane >= off) iv += u;
    }
    __shared__ int ws[4];
    if (lane == 63) ws[wv] = iv;
    __syncthreads();
    int woff = blockoff[blockIdx.x];
    for (int j = 0; j < wv; ++j) woff += ws[j];
    int ex = woff + iv - v;
    if (i < n) { rowptr[i] = ex; wp[i] = ex; }
    if (i == n - 1) rowptr[n] = ex + v;
}

__global__ __launch_bounds__(256) void fill_kernel(
    const int* __restrict__ ei, int* __restrict__ wp,
    int* __restrict__ adjsrc, int E)
{
    int e = blockIdx.x * 256 + threadIdx.x;
    if (e < E) {
        int dst = ei[E + e];
        int slot = atomicAdd(&wp[dst], 1);
        adjsrc[slot] = ei[e];
    }
}

// ---------------------------------------------------------------------------
// mom[n][k] = sum of eattr over in-edges. Edge-parallel scatter:
// coalesced ei/eattr reads, atomics into L2-resident 3.2MB region.
// ---------------------------------------------------------------------------
__global__ __launch_bounds__(256) void mom_scatter(
    const int* __restrict__ ei, const float* __restrict__ eattr,
    float* __restrict__ mom, int E)
{
    int t = blockIdx.x * 256 + threadIdx.x;
    int e = t >> 4, k = t & 15;
    if (e < E)
        atomicAdd(&mom[(size_t)ei[E + e] * 16 + k], eattr[(size_t)e * 16 + k]);
}

// ---------------------------------------------------------------------------
// Gather aggregation over bf16 h (16-deep unrolled for MLP):
// ag[n] = bf16( h[n] + Σ_in h[src] + be*(deg+1) + We·mom[n] )
// ---------------------------------------------------------------------------
__global__ __launch_bounds__(256) void aggregate_kernel(
    const unsigned short* __restrict__ h, const int* __restrict__ adjsrc,
    const int* __restrict__ rowptr, const float* __restrict__ mom,
    const float* __restrict__ We, const float* __restrict__ be,
    unsigned short* __restrict__ ag, int N)
{
    const int lane = threadIdx.x & 63;
    const int gwave = (blockIdx.x * 256 + threadIdx.x) >> 6;
    const int nwaves = (gridDim.x * 256) >> 6;
    const int c0 = 2 * lane;

    float w0[16], w1[16];
#pragma unroll
    for (int k = 0; k < 16; ++k) {
        w0[k] = We[c0 * 16 + k];
        w1[k] = We[(c0 + 1) * 16 + k];
    }
    const float b0 = be[c0], b1 = be[c0 + 1];

    for (int n = gwave; n < N; n += nwaves) {
        const int s = rowptr[n], e = rowptr[n + 1];
        unsigned int self = *reinterpret_cast<const unsigned int*>(
            h + (size_t)n * 128 + c0);
        float ax = bflo(self), ay = bfhi(self);
        float mval = (lane < 16) ? mom[(size_t)n * 16 + lane] : 0.f;

        int p = s;
        for (; p + 16 <= e; p += 16) {
            int sv[16]; unsigned int vv[16];
#pragma unroll
            for (int j = 0; j < 16; ++j) sv[j] = adjsrc[p + j];
#pragma unroll
            for (int j = 0; j < 16; ++j)
                vv[j] = *reinterpret_cast<const unsigned int*>(
                    h + (size_t)sv[j] * 128 + c0);
#pragma unroll
            for (int j = 0; j < 16; ++j) { ax += bflo(vv[j]); ay += bfhi(vv[j]); }
        }
        for (; p + 4 <= e; p += 4) {
            int sv[4]; unsigned int vv[4];
#pragma unroll
            for (int j = 0; j < 4; ++j) sv[j] = adjsrc[p + j];
#pragma unroll
            for (int j = 0; j < 4; ++j)
                vv[j] = *reinterpret_cast<const unsigned int*>(
                    h + (size_t)sv[j] * 128 + c0);
#pragma unroll
            for (int j = 0; j < 4; ++j) { ax += bflo(vv[j]); ay += bfhi(vv[j]); }
        }
        for (; p < e; ++p) {
            int sv = adjsrc[p];
            unsigned int v = *reinterpret_cast<const unsigned int*>(
                h + (size_t)sv * 128 + c0);
            ax += bflo(v); ay += bfhi(v);
        }

        const float degp1 = (float)(e - s + 1);
        float d0 = b0 * degp1, d1 = b1 * degp1;
#pragma unroll
        for (int k = 0; k < 16; ++k) {
            const float sk = __shfl(mval, k);
            d0 += w0[k] * sk; d1 += w1[k] * sk;
        }
        ax += d0; ay += d1;
        *reinterpret_cast<unsigned int*>(ag + (size_t)n * 128 + c0) = packbf(ax, ay);
    }
}

// ---------------------------------------------------------------------------
// BN apply + relu: bf16 h2 -> bf16 h  (uses precomputed coef)
// ---------------------------------------------------------------------------
__global__ __launch_bounds__(256) void bn_apply_bf16(
    const unsigned short* __restrict__ h2b, const float* __restrict__ coef,
    unsigned short* __restrict__ h, int total4)
{
    int tid = blockIdx.x * 256 + threadIdx.x;
    int c4 = (tid * 4) & 127;
    float sc[4], sh[4];
#pragma unroll
    for (int j = 0; j < 4; ++j) {
        sc[j] = coef[c4 + j];
        sh[j] = coef[128 + c4 + j];
    }
    int stride = gridDim.x * 256;
    for (int i = tid; i < total4; i += stride) {
        uint2 in = reinterpret_cast<const uint2*>(h2b)[i];
        float x0 = fmaxf(sc[0] * bflo(in.x) + sh[0], 0.f);
        float x1 = fmaxf(sc[1] * bfhi(in.x) + sh[1], 0.f);
        float x2 = fmaxf(sc[2] * bflo(in.y) + sh[2], 0.f);
        float x3 = fmaxf(sc[3] * bfhi(in.y) + sh[3], 0.f);
        uint2 o; o.x = packbf(x0, x1); o.y = packbf(x2, x3);
        reinterpret_cast<uint2*>(h)[i] = o;
    }
}

// ---------------------------------------------------------------------------
// Pool stage 1: segmented sum over sorted batch keys (bf16 h2)
// ---------------------------------------------------------------------------
__global__ __launch_bounds__(256) void pool_part(
    const unsigned short* __restrict__ h2b, const int* __restrict__ batch,
    float* __restrict__ pooled, int N)
{
    const int per = (N + gridDim.x - 1) / gridDim.x;
    const int start = blockIdx.x * per;
    const int end = min(start + per, N);
    if (start >= end) return;
    const int c = threadIdx.x & 127;
    const int sub = threadIdx.x >> 7;
    int g_cur = batch[start];
    float acc = 0.f;
    for (int n = start + sub; n < end; n += 2) {
        int g = batch[n];
        if (g != g_cur) {
            if (acc != 0.f) atomicAdd(&pooled[(size_t)g_cur * 128 + c], acc);
            acc = 0.f; g_cur = g;
        }
        acc += bf2f(h2b[(size_t)n * 128 + c]);
    }
    if (acc != 0.f) atomicAdd(&pooled[(size_t)g_cur * 128 + c], acc);
}

// ---------------------------------------------------------------------------
// Pool stage 2: mean + folded final BN affine (coef) + head dot
// ---------------------------------------------------------------------------
__global__ __launch_bounds__(128) void head_final(
    const float* __restrict__ pooled, const int* __restrict__ batch,
    const float* __restrict__ coef, const float* __restrict__ Wp,
    const float* __restrict__ bp, float* __restrict__ out, int N)
{
    const int g = blockIdx.x;
    __shared__ int sb[2];
    if (threadIdx.x < 2) {
        int target = g + threadIdx.x;
        int lo = 0, hi = N;
        while (lo < hi) {
            int mid = (lo + hi) >> 1;
            if (batch[mid] < target) lo = mid + 1; else hi = mid;
        }
        sb[threadIdx.x] = lo;
    }
    __syncthreads();
    const float cntf = fmaxf((float)(sb[1] - sb[0]), 1.f);
    const int c = threadIdx.x;
    float m = pooled[(size_t)g * 128 + c] / cntf;
    float v = (coef[c] * m + coef[128 + c]) * Wp[c];
    const int lane = threadIdx.x & 63;
#pragma unroll
    for (int off = 32; off > 0; off >>= 1) v += __shfl_down(v, off);
    __shared__ float wsum[2];
    if (lane == 0) wsum[threadIdx.x >> 6] = v;
    __syncthreads();
    if (threadIdx.x == 0) out[g] = wsum[0] + wsum[1] + bp[0];
}

// ---------------------------------------------------------------------------
extern "C" void kernel_launch(void* const* d_in, const int* in_sizes, int n_in,
                              void* d_out, int out_size, void* d_ws, size_t ws_size,
                              hipStream_t stream)
{
    const float* x     = (const float*)d_in[0];
    const float* eattr = (const float*)d_in[1];
    const float* W0    = (const float*)d_in[2];
    const float* b0    = (const float*)d_in[3];
    const float* We    = (const float*)d_in[4];
    const float* be    = (const float*)d_in[5];
    const float* W1    = (const float*)d_in[6];
    const float* b1    = (const float*)d_in[7];
    const float* W2    = (const float*)d_in[8];
    const float* b2    = (const float*)d_in[9];
    const float* gamma = (const float*)d_in[10];
    const float* beta  = (const float*)d_in[11];
    const float* Wp    = (const float*)d_in[12];
    const float* bp    = (const float*)d_in[13];
    const int* ei    = (const int*)d_in[14];
    const int* batch = (const int*)d_in[15];

    const int N = in_sizes[0] / 32;   // 50000
    const int E = in_sizes[1] / 16;   // 800000

    char* ws = (char*)d_ws;
    size_t off = 0;
    auto alloc = [&](size_t bytes) { char* p = ws + off; off += (bytes + 255) & ~(size_t)255; return p; };
    unsigned short* hb  = (unsigned short*)alloc((size_t)N * 128 * 2);
    unsigned short* ag  = (unsigned short*)alloc((size_t)N * 128 * 2);
    unsigned short* h2b = (unsigned short*)alloc((size_t)N * 128 * 2);
    // deg_cnt / wp alias h2b region (dead before first fused_mlp write)
    int* deg_cnt = (int*)h2b;
    int* wp      = ((int*)h2b) + N;
    float* sums2   = (float*)alloc(32 * 256 * 4);
    float* coef    = (float*)alloc(256 * 4);
    float* pooled  = (float*)alloc(NGRAPHS * 128 * 4);
    float* mom     = (float*)alloc((size_t)N * 16 * 4);
    unsigned short* W0bf = (unsigned short*)alloc(128 * 32 * 2);
    unsigned short* W1bf = (unsigned short*)alloc(3 * 256 * 128 * 2);
    unsigned short* W2bf = (unsigned short*)alloc(3 * 128 * 256 * 2);
    int* rowptr   = (int*)alloc(((size_t)N + 1) * 4);
    int* blocksum = (int*)alloc(256 * 4);
    int* adjsrc   = (int*)alloc((size_t)E * 4);

    const dim3 blk(256);
    const int mblocks = (N + 63) / 64;
    const int ntiles = (N + 15) / 16;
    const int total4 = N * 32;
    const int eblocks = (E + 255) / 256;
    const int sblocks = (N + 255) / 256;   // <=256
    const float invN = 1.0f / (float)N;

    // --- edge-attr moments (independent of CSR) + CSR build ---
    hipMemsetAsync(mom, 0, (size_t)N * 16 * 4, stream);
    hipMemsetAsync(deg_cnt, 0, (size_t)N * 4, stream);
    mom_scatter<<<dim3((E * 16 + 255) / 256), blk, 0, stream>>>(ei, eattr, mom, E);
    hist_kernel<<<dim3(eblocks), blk, 0, stream>>>(ei, deg_cnt, E);
    scan_part<<<dim3(sblocks), blk, 0, stream>>>(deg_cnt, blocksum, N);
    scan_top<<<dim3(1), blk, 0, stream>>>(blocksum, sblocks);
    scan_emit<<<dim3(sblocks), blk, 0, stream>>>(deg_cnt, blocksum, rowptr, wp, N);
    fill_kernel<<<dim3(eblocks), blk, 0, stream>>>(ei, wp, adjsrc, E);

    // --- weight pre-conversion ---
    conv_bf16_3<<<dim3(384), blk, 0, stream>>>(
        W0, W0bf, 128 * 32, W1, W1bf, 3 * 256 * 128, W2, W2bf, 3 * 128 * 256);

    // h = bf16(x @ W0^T + b0)
    gemm_bt<32, false, false, true><<<dim3(mblocks, 2), blk, 0, stream>>>(
        x, W0bf, b0, (void*)hb, N, 128);

    for (int l = 0; l < LAYERS; ++l) {
        hipMemsetAsync(sums2, 0, 32 * 256 * 4, stream);
        aggregate_kernel<<<dim3(4096), blk, 0, stream>>>(
            hb, adjsrc, rowptr, mom, We + l * 128 * 16, be + l * 128, ag, N);
        fused_mlp<<<dim3(640), dim3(512), 0, stream>>>(
            ag, W1bf + l * 256 * 128, b1 + l * 256,
            W2bf + l * 128 * 256, b2 + l * 128, h2b, sums2, N, ntiles);
        bn_coef<<<dim3(1), dim3(128), 0, stream>>>(
            sums2, gamma + l * 128, beta + l * 128, coef, invN);
        if (l < LAYERS - 1)
            bn_apply_bf16<<<dim3(1024), blk, 0, stream>>>(h2b, coef, hb, total4);
    }

    // --- two-stage mean pool + folded final BN + head ---
    hipMemsetAsync(pooled, 0, NGRAPHS * 128 * 4, stream);
    pool_part<<<dim3(784), blk, 0, stream>>>(h2b, batch, pooled, N);
    head_final<<<dim3(NGRAPHS), dim3(128), 0, stream>>>(
        pooled, batch, coef, Wp, bp, (float*)d_out, N);
}